// Round 6
// baseline (314.238 us; speedup 1.0000x reference)
//
#include <hip/hip_runtime.h>

// Forward-fill: out[r,t] = att[r, last index <= t where wet==0], t=0 forced dry.
// wet is int32 (harness converts bool -> int32).
//
// Chain-free wave version: each WAVE owns 2048 elems = 8 chunks of 256.
// carry_k depends only on INPUT data (anyDry(k-1) ? lastDryVal(k-1) :
// carry_{k-1}), not on the previous chunk's fill -- so all 8 chunk summaries
// (ballot + bpermute) are independent and fully pipelined. The wave-entry
// carry comes from one speculative 64-wide lookback load of wet AND att
// (single round trip), with a loop fallback for adversarial all-wet windows.
// No LDS, no __syncthreads, no inter-chunk register chain.

constexpr int K      = 8;                 // chunks per wave
constexpr int WCHUNK = 256;               // elems per chunk (64 lanes x 4)
constexpr int WSEG   = K * WCHUNK;        // 2048 elems per wave

typedef float f4v __attribute__((ext_vector_type(4)));

__global__ __launch_bounds__(256) void ffill_kernel(
    const float* __restrict__ att,
    const int* __restrict__ wet,
    float* __restrict__ out,
    int T, int segsPerRow)
{
    const int lane = threadIdx.x & 63;
    const int wid  = threadIdx.x >> 6;
    const int s    = blockIdx.x * 4 + wid;     // segment index within row
    if (s >= segsPerRow) return;               // wave-uniform exit
    const int r    = blockIdx.y;
    const long long rowBase = (long long)r * T;
    const int base = s * WSEG;

    // ---- speculative lookback loads (issued first; independent) ----
    float att_lb = 0.0f; int wet_lb = 1;
    if (base > 0) {                            // window [base-64, base); base>=2048 so idx>=1984
        const int idx = base - 64 + lane;
        att_lb = att[rowBase + idx];
        wet_lb = wet[rowBase + idx];
    }

    // ---- main loads: all 16 dwordx4 issued back-to-back ----
    const int e0 = base + lane * 4;
    float4 a[K]; int4 w[K];
    #pragma unroll
    for (int k = 0; k < K; ++k) {
        const int e = e0 + k * WCHUNK;
        if (e < T) {                           // T % 4 == 0 -> all-or-nothing per lane
            a[k] = *reinterpret_cast<const float4*>(att + rowBase + e);
            w[k] = *reinterpret_cast<const int4*>(wet + rowBase + e);
        } else {
            a[k] = make_float4(0.f, 0.f, 0.f, 0.f);
            w[k] = make_int4(1, 1, 1, 1);
        }
    }

    // ---- per-chunk independent summaries (full ILP across chunks) ----
    bool  d0v[K], d1v[K], d2v[K], d3v[K];
    bool  anyDry[K];                           // chunk has >=1 dry
    float lastDry[K];                          // value at chunk's last dry pos (valid if anyDry)
    float preVal[K];  bool preHas[K];          // rightmost dry among LOWER lanes
    #pragma unroll
    for (int k = 0; k < K; ++k) {
        const int e = e0 + k * WCHUNK;
        const bool valid = (e < T);
        bool d0 = (w[k].x == 0) || (e == 0);   // forced dry at t=0
        bool d1 = (w[k].y == 0);
        bool d2 = (w[k].z == 0);
        bool d3 = (w[k].w == 0);
        if (!valid) { d0 = d1 = d2 = d3 = false; }
        d0v[k] = d0; d1v[k] = d1; d2v[k] = d2; d3v[k] = d3;

        const bool has = d0 | d1 | d2 | d3;
        const float lastval = d3 ? a[k].w : (d2 ? a[k].z : (d1 ? a[k].y : a[k].x));

        const unsigned long long mask = __ballot(has);
        anyDry[k] = (mask != 0ull);
        const int wsrc = anyDry[k] ? (63 - __clzll(mask)) : 0;
        lastDry[k] = __shfl(lastval, wsrc);

        const unsigned long long pm = mask & ((1ull << lane) - 1ull);
        preHas[k] = (pm != 0ull);
        const int psrc = preHas[k] ? (63 - __clzll(pm)) : 0;
        preVal[k] = __shfl(lastval, psrc);
    }

    // ---- wave-entry carry from the speculative lookback ----
    float carry = 0.0f;                        // unused for s==0 (t=0 forced dry)
    if (base > 0) {
        const unsigned long long m = __ballot(wet_lb == 0);
        if (m != 0ull) {
            carry = __shfl(att_lb, 63 - __clzll(m));
        } else {
            // adversarial fallback: walk back (terminates at forced-dry t=0)
            int hi = base - 64;
            while (hi > 0) {
                const int start = (hi >= 64) ? (hi - 64) : 0;
                const int idx   = start + lane;
                const bool dry  = (idx < hi) && ((wet[rowBase + idx] == 0) || (idx == 0));
                const unsigned long long mm = __ballot(dry);
                if (mm != 0ull) {
                    carry = att[rowBase + start + (63 - __clzll(mm))];
                    break;
                }
                hi = start;
            }
        }
    }

    // ---- resolve (8 cndmasks) + independent fills/stores ----
    #pragma unroll
    for (int k = 0; k < K; ++k) {
        const int e = e0 + k * WCHUNK;
        const float carry_in = preHas[k] ? preVal[k] : carry;

        float running = carry_in;
        f4v o;
        running = d0v[k] ? a[k].x : running;  o.x = running;
        running = d1v[k] ? a[k].y : running;  o.y = running;
        running = d2v[k] ? a[k].z : running;  o.z = running;
        running = d3v[k] ? a[k].w : running;  o.w = running;
        if (e < T) {
            __builtin_nontemporal_store(o, reinterpret_cast<f4v*>(out + rowBase + e));
        }

        carry = anyDry[k] ? lastDry[k] : carry;   // data-only dependence
    }
}

extern "C" void kernel_launch(void* const* d_in, const int* in_sizes, int n_in,
                              void* d_out, int out_size, void* d_ws, size_t ws_size,
                              hipStream_t stream) {
    const float* att = (const float*)d_in[0];
    const int* wet   = (const int*)d_in[1];
    float* out       = (float*)d_out;

    const int B = 64;
    const int T = in_sizes[0] / B;                      // 500000
    const int segsPerRow = (T + WSEG - 1) / WSEG;       // 245
    const int blocksX = (segsPerRow + 3) / 4;           // 62

    dim3 grid(blocksX, B);
    dim3 block(256);
    ffill_kernel<<<grid, block, 0, stream>>>(att, wet, out, T, segsPerRow);
}

// Round 7
// 294.296 us; speedup vs baseline: 1.0678x; 1.0678x over previous
//
#include <hip/hip_runtime.h>

// Forward-fill: out[r,t] = att[r, last index <= t where wet==0], t=0 forced dry.
// wet is int32 (harness converts bool -> int32).
//
// Many-lightweight-waves version (R2 shape, barrier-free): each WAVE handles
// ONE 256-elem chunk. All loads (main float4/int4 + speculative 64-elem
// lookback of wet AND att) are issued in one burst; carry-in is resolved from
// the lookback ballot with no second memory round-trip. A never-taken-in-
// practice walk-back loop covers adversarial all-wet windows (terminates at
// forced-dry t=0). No LDS, no __syncthreads. Bijective XCD swizzle keeps
// consecutive chunks of a row on one XCD so lookback hits L2.

constexpr int CHUNK = 256;                 // elems per wave (64 lanes x 4)

typedef float f4v __attribute__((ext_vector_type(4)));

__global__ __launch_bounds__(256) void ffill_kernel(
    const float* __restrict__ att,
    const int* __restrict__ wet,
    float* __restrict__ out,
    int T, int chunksPerRow)
{
    // ---- bijective XCD swizzle (8 XCDs): consecutive swizzled ids -> same XCD ----
    const int nwg = gridDim.x;
    const int q   = nwg >> 3;
    const int rr  = nwg & 7;
    const int xcd = blockIdx.x & 7;
    const int bix = blockIdx.x >> 3;
    const int bswz = (xcd < rr ? xcd * (q + 1) : rr * (q + 1) + (xcd - rr) * q) + bix;

    const int lane = threadIdx.x & 63;
    const int wid  = threadIdx.x >> 6;
    const int c    = bswz * 4 + wid;           // chunk index within row
    if (c >= chunksPerRow) return;             // wave-uniform exit
    const int r    = blockIdx.y;
    const long long rowBase = (long long)r * T;
    const int base = c * CHUNK;

    // ---- issue ALL loads up-front (independent; one burst) ----
    float att_lb = 0.0f; int wet_lb = 1;
    if (base > 0) {                            // window [base-64, base); base>=256
        const int i = base - 64 + lane;
        att_lb = att[rowBase + i];
        wet_lb = wet[rowBase + i];
    }

    const int e = base + lane * 4;
    const bool valid = (e < T);                // T % 4 == 0 -> all-or-nothing per lane
    float4 a = make_float4(0.f, 0.f, 0.f, 0.f);
    int4  w = make_int4(1, 1, 1, 1);
    if (valid) {
        a = *reinterpret_cast<const float4*>(att + rowBase + e);
        w = *reinterpret_cast<const int4*>(wet + rowBase + e);
    }

    // ---- wave-entry carry from the speculative lookback ----
    float carry = 0.0f;                        // unused for c==0 (t=0 forced dry)
    if (base > 0) {
        const unsigned long long m = __ballot(wet_lb == 0);
        if (m != 0ull) {
            carry = __shfl(att_lb, 63 - __clzll(m));
        } else {
            // adversarial fallback: walk back (terminates at forced-dry t=0)
            int hi = base - 64;
            while (hi > 0) {
                const int start = (hi >= 64) ? (hi - 64) : 0;
                const int idx   = start + lane;
                const bool dry  = (idx < hi) && ((wet[rowBase + idx] == 0) || (idx == 0));
                const unsigned long long mm = __ballot(dry);
                if (mm != 0ull) {
                    carry = att[rowBase + start + (63 - __clzll(mm))];
                    break;
                }
                hi = start;
            }
        }
    }

    // ---- per-lane dry flags ----
    bool d0 = (w.x == 0) || (e == 0);          // forced dry at t=0
    bool d1 = (w.y == 0);
    bool d2 = (w.z == 0);
    bool d3 = (w.w == 0);
    if (!valid) { d0 = d1 = d2 = d3 = false; }

    const bool has = d0 | d1 | d2 | d3;
    const float lastval = d3 ? a.w : (d2 ? a.z : (d1 ? a.y : a.x));

    // ---- carry-in: rightmost dry among lower lanes, else lookback carry ----
    const unsigned long long mask = __ballot(has);
    const unsigned long long pm   = mask & ((1ull << lane) - 1ull);
    const int   psrc = (pm != 0ull) ? (63 - __clzll(pm)) : 0;
    const float pval = __shfl(lastval, psrc);
    const float carry_in = (pm != 0ull) ? pval : carry;

    // ---- sequential fill over the lane's 4 elements, vector store ----
    if (valid) {
        float running = carry_in;
        f4v o;
        running = d0 ? a.x : running;  o.x = running;
        running = d1 ? a.y : running;  o.y = running;
        running = d2 ? a.z : running;  o.z = running;
        running = d3 ? a.w : running;  o.w = running;
        *reinterpret_cast<f4v*>(out + rowBase + e) = o;
    }
}

extern "C" void kernel_launch(void* const* d_in, const int* in_sizes, int n_in,
                              void* d_out, int out_size, void* d_ws, size_t ws_size,
                              hipStream_t stream) {
    const float* att = (const float*)d_in[0];
    const int* wet   = (const int*)d_in[1];
    float* out       = (float*)d_out;

    const int B = 64;
    const int T = in_sizes[0] / B;                          // 500000
    const int chunksPerRow = (T + CHUNK - 1) / CHUNK;       // 1954
    const int blocksX = (chunksPerRow + 3) / 4;             // 489

    dim3 grid(blocksX, B);
    dim3 block(256);
    ffill_kernel<<<grid, block, 0, stream>>>(att, wet, out, T, chunksPerRow);
}